// Round 1
// baseline (263.976 us; speedup 1.0000x reference)
//
#include <hip/hip_runtime.h>

// MHA: B=2, S=2048, D=1024, H=16, HD=64. fp32 in/out, bf16 MFMA internally.
// ws layout (64 MB): qb/kb/vb bf16 [4096,1024] @0/8/16MB; Wq/k/v/o^T bf16
// [1024,1024] @24/26/28/30MB; q(pre-scaled 0.125*log2e),k [B,H,S,HD] @32/40MB;
// v^T [B,H,HD,S] @48MB; bm u64[2048][32] @56MB; ctx bf16 @16MB (aliases vb).
//
// R10: flash rewritten around mfma_32x32x16 (2x FLOP per LDS byte) with the
// P-matrix kept entirely in registers (perm-pack + v_permlane32_swap_b32),
// Q-fragments loaded direct from global, l = P@ones MFMA (same C-layout as O),
// and double-buffered K/V LDS with ONE barrier per 64-key tile. LDS wave-ops
// per CU-iter drop 384 -> 160; flash was LDS-pipe-bound (model ~62us ~= 66us
// observed, MfmaUtil only 24%). proj3/gemm_out = R6 config (unchanged).

using s8v = __attribute__((ext_vector_type(8))) short;   // 8 bf16 (4 VGPRs)
using f4v = __attribute__((ext_vector_type(4))) float;   // MFMA acc (16x16)
using f16v = __attribute__((ext_vector_type(16))) float; // MFMA acc (32x32)
typedef unsigned long long u64;

__device__ __forceinline__ unsigned short f2bf(float f) {
  union { float f; unsigned int u; } v; v.f = f;
  return (unsigned short)((v.u + 0x7fffu + ((v.u >> 16) & 1u)) >> 16);  // RNE
}

// pack two f32 -> two bf16 (truncation, same as prior perm path): lo | hi<<16
__device__ __forceinline__ unsigned pkbf(float lo, float hi2) {
  return __builtin_amdgcn_perm(__float_as_uint(hi2), __float_as_uint(lo), 0x07060302);
}

__device__ __forceinline__ void gll16(const void* g, void* l) {
  __builtin_amdgcn_global_load_lds(
      (const __attribute__((address_space(1))) unsigned int*)g,
      (__attribute__((address_space(3))) unsigned int*)l, 16, 0, 0);
}

// ---------- merged prep: f2b (QKV), wtrans (4 weights), packmask ----------
__global__ void prep_kernel(const float* __restrict__ Q, const float* __restrict__ K,
                            const float* __restrict__ V,
                            unsigned short* __restrict__ qb, unsigned short* __restrict__ kb,
                            unsigned short* __restrict__ vb,
                            const float* __restrict__ W0, const float* __restrict__ W1,
                            const float* __restrict__ W2, const float* __restrict__ W3,
                            unsigned short* __restrict__ T0, unsigned short* __restrict__ T1,
                            unsigned short* __restrict__ T2, unsigned short* __restrict__ T3,
                            const int* __restrict__ mask, u64* __restrict__ bm) {
  __shared__ unsigned short t[64][72];
  const int bid = blockIdx.x, tid = threadIdx.x;
  if (bid < 12288) {
    int z = bid >> 12;
    int idx = (bid & 4095) * 256 + tid;
    const float* in = (z == 0) ? Q : (z == 1) ? K : V;
    unsigned short* out = (z == 0) ? qb : (z == 1) ? kb : vb;
    float4 v = ((const float4*)in)[idx];
    ushort4 o;
    o.x = f2bf(v.x); o.y = f2bf(v.y); o.z = f2bf(v.z); o.w = f2bf(v.w);
    ((ushort4*)out)[idx] = o;
  } else if (bid < 13312) {
    int b = bid - 12288;
    int z = b >> 8, rem = b & 255;
    int k0 = (rem >> 4) * 64, n0 = (rem & 15) * 64;
    const float* W = (z == 0) ? W0 : (z == 1) ? W1 : (z == 2) ? W2 : W3;
    unsigned short* Wt = (z == 0) ? T0 : (z == 1) ? T1 : (z == 2) ? T2 : T3;
    for (int p = 0; p < 4; ++p) {
      int idx = p * 256 + tid;
      int row = idx >> 4, c4 = idx & 15;
      float4 v = *(const float4*)&W[(size_t)(k0 + row) * 1024 + n0 + c4 * 4];
      t[row][c4 * 4 + 0] = f2bf(v.x);
      t[row][c4 * 4 + 1] = f2bf(v.y);
      t[row][c4 * 4 + 2] = f2bf(v.z);
      t[row][c4 * 4 + 3] = f2bf(v.w);
    }
    __syncthreads();
    for (int p = 0; p < 2; ++p) {
      int idx = p * 256 + tid;
      int j = idx >> 3, c8 = idx & 7;
      unsigned short tmp[8];
      for (int i = 0; i < 8; ++i) tmp[i] = t[c8 * 8 + i][j];
      uint4 o;
      o.x = tmp[0] | ((unsigned)tmp[1] << 16);
      o.y = tmp[2] | ((unsigned)tmp[3] << 16);
      o.z = tmp[4] | ((unsigned)tmp[5] << 16);
      o.w = tmp[6] | ((unsigned)tmp[7] << 16);
      *(uint4*)&Wt[(size_t)(n0 + j) * 1024 + k0 + c8 * 8] = o;
    }
  } else {
    int b = bid - 13312;
    int gw = (b * 256 + tid) >> 6;
    int lane = tid & 63;
    int mv = mask[(size_t)gw * 64 + lane];
    u64 bal = __ballot(mv != 0);
    if (lane == 0) bm[gw] = bal;
  }
}

// ---------- fused QKV projection GEMM, 64x128 tile (R6 config) ----------
// z=0: q*(0.125*log2e) -> [B,H,S,HD]; z=1: k -> [B,H,S,HD]; z=2: v -> v^T [B,H,HD,S]
__global__ __launch_bounds__(256) void proj3_kernel(
    const unsigned short* __restrict__ A0, const unsigned short* __restrict__ A1,
    const unsigned short* __restrict__ A2,
    const unsigned short* __restrict__ W0, const unsigned short* __restrict__ W1,
    const unsigned short* __restrict__ W2,
    const float* __restrict__ b0, const float* __restrict__ b1, const float* __restrict__ b2,
    unsigned short* __restrict__ oq, unsigned short* __restrict__ ok,
    unsigned short* __restrict__ ovt) {
  const int z = blockIdx.z;
  const unsigned short* A  = (z == 0) ? A0 : (z == 1) ? A1 : A2;
  const unsigned short* Wt = (z == 0) ? W0 : (z == 1) ? W1 : W2;
  const float* bias        = (z == 0) ? b0 : (z == 1) ? b1 : b2;

  __shared__ __align__(16) unsigned short As[64 * 32];
  __shared__ __align__(16) unsigned short Bs[128 * 32];

  const int tid = threadIdx.x;
  const int lane = tid & 63, w = tid >> 6, ln = lane & 15, quad = lane >> 4;
  const int wm = (w & 1) * 32, wn = (w >> 1) * 64;
  const int m0 = blockIdx.x * 64, n0 = blockIdx.y * 128;

  const int slr = lane >> 2;
  const int schunk = (lane & 3) ^ ((lane >> 3) & 3);
  const int cfrag = (quad ^ ((ln >> 1) & 3)) * 8;

  f4v zero = {0.f, 0.f, 0.f, 0.f};
  f4v acc[2][4];
  for (int mi = 0; mi < 2; ++mi)
    for (int ni = 0; ni < 4; ++ni) acc[mi][ni] = zero;

  for (int kt = 0; kt < 1024; kt += 32) {
    __syncthreads();
    gll16(&A[(size_t)(m0 + w * 16 + slr) * 1024 + kt + schunk * 8],        &As[(w * 16) * 32]);
    gll16(&Wt[(size_t)(n0 + w * 32 + slr) * 1024 + kt + schunk * 8],       &Bs[(w * 32) * 32]);
    gll16(&Wt[(size_t)(n0 + w * 32 + 16 + slr) * 1024 + kt + schunk * 8],  &Bs[(w * 32 + 16) * 32]);
    __syncthreads();
    s8v a[2], b[4];
    for (int mi = 0; mi < 2; ++mi) a[mi] = *(const s8v*)&As[(wm + mi * 16 + ln) * 32 + cfrag];
    for (int ni = 0; ni < 4; ++ni) b[ni] = *(const s8v*)&Bs[(wn + ni * 16 + ln) * 32 + cfrag];
    if (z < 2) {
      for (int mi = 0; mi < 2; ++mi)
        for (int ni = 0; ni < 4; ++ni)
          acc[mi][ni] = __builtin_amdgcn_mfma_f32_16x16x32_bf16(a[mi], b[ni], acc[mi][ni], 0, 0, 0);
    } else {
      for (int mi = 0; mi < 2; ++mi)
        for (int ni = 0; ni < 4; ++ni)
          acc[mi][ni] = __builtin_amdgcn_mfma_f32_16x16x32_bf16(b[ni], a[mi], acc[mi][ni], 0, 0, 0);
    }
  }

  if (z < 2) {
    const float qscale = (z == 0) ? 0.18033688f : 1.0f;  // 0.125 * log2(e)
    unsigned short* outp = (z == 0) ? oq : ok;
    for (int mi = 0; mi < 2; ++mi) {
      int rb = m0 + wm + mi * 16 + quad * 4;
      int b_ = rb >> 11;
      for (int ni = 0; ni < 4; ++ni) {
        int col = n0 + wn + ni * 16 + ln;
        float bvv = bias[col];
        int h = col >> 6, hd = col & 63;
        size_t ob = (size_t)(b_ * 16 + h) * 2048;
        for (int r = 0; r < 4; ++r) {
          int s = (rb + r) & 2047;
          outp[(ob + s) * 64 + hd] = f2bf((acc[mi][ni][r] + bvv) * qscale);
        }
      }
    }
  } else {
    for (int ni = 0; ni < 4; ++ni) {
      for (int r = 0; r < 4; ++r) {
        int colw = n0 + wn + ni * 16 + quad * 4 + r;
        int h = colw >> 6, hd = colw & 63;
        float bvv = bias[colw];
        for (int mi = 0; mi < 2; ++mi) {
          int sg = m0 + wm + mi * 16 + ln;
          int b_ = sg >> 11, ss = sg & 2047;
          ovt[((size_t)(b_ * 16 + h) * 64 + hd) * 2048 + ss] = f2bf(acc[mi][ni][r] + bvv);
        }
      }
    }
  }
}

// ---------- flash attention R10: 256 threads, 4 waves x 32 q-rows, 32x32x16 ----------
// S^T = K.Q^T via mfma_32x32x16 (C: col=lane&31=q, row=(r&3)+8*(r>>2)+4*hi=key).
// P stays in registers: pack pairs with v_perm, two v_permlane32_swap_b32 per
// 16-key chunk rebuild the PV A-frag (row=lane&31=q, k=hi*8+j=key).
// l = P @ ones (same C layout as O -> per-reg 1/l, no redistribution).
// K/V double-buffered in LDS, one __syncthreads per 64-key tile.
__global__ __launch_bounds__(256) void flash_kernel(
    const unsigned short* __restrict__ q, const unsigned short* __restrict__ k,
    const unsigned short* __restrict__ vt, const u64* __restrict__ bm,
    unsigned short* __restrict__ ctx) {
  __shared__ __align__(16) unsigned short k_s[2][64][72];
  __shared__ __align__(16) unsigned short v_s[2][64][72];

  const int tid = threadIdx.x;
  const int lane = tid & 63, w = tid >> 6;
  const int l31 = lane & 31, hi = lane >> 5;
  const int q0 = blockIdx.x * 128;
  const int bh = blockIdx.y;
  const unsigned short* qg  = q  + ((size_t)bh * 2048 + q0) * 64;
  const unsigned short* kgb = k  + (size_t)bh * 2048 * 64;
  const unsigned short* vgb = vt + (size_t)bh * 64 * 2048;

  // Q fragments direct from global: wave w owns q-rows [w*32, w*32+32)
  const int qrow = w * 32 + l31;
  s8v qf[4];
#pragma unroll
  for (int c = 0; c < 4; ++c)
    qf[c] = *(const s8v*)&qg[(size_t)qrow * 64 + c * 16 + hi * 8];

  const u64* bmr = bm + (size_t)(q0 + qrow) * 32;

  // ones fragment for l = P @ ones
  s8v ones;
#pragma unroll
  for (int i = 0; i < 8; ++i) ones[i] = (short)0x3F80;

  // staging: 256 threads x 2 uint4 per array per tile
  const int srow = tid >> 3, sc8 = tid & 7;  // rows srow and srow+32

  // tile 0 -> LDS buf 0; prefetch tile 1 into regs
  uint4 kr0 = *(const uint4*)&kgb[(size_t)srow * 64 + sc8 * 8];
  uint4 kr1 = *(const uint4*)&kgb[(size_t)(srow + 32) * 64 + sc8 * 8];
  uint4 vr0 = *(const uint4*)&vgb[(size_t)srow * 2048 + sc8 * 8];
  uint4 vr1 = *(const uint4*)&vgb[(size_t)(srow + 32) * 2048 + sc8 * 8];
  *(uint4*)&k_s[0][srow][sc8 * 8] = kr0;
  *(uint4*)&k_s[0][srow + 32][sc8 * 8] = kr1;
  *(uint4*)&v_s[0][srow][sc8 * 8] = vr0;
  *(uint4*)&v_s[0][srow + 32][sc8 * 8] = vr1;
  kr0 = *(const uint4*)&kgb[(size_t)(64 + srow) * 64 + sc8 * 8];
  kr1 = *(const uint4*)&kgb[(size_t)(64 + srow + 32) * 64 + sc8 * 8];
  vr0 = *(const uint4*)&vgb[(size_t)srow * 2048 + 64 + sc8 * 8];
  vr1 = *(const uint4*)&vgb[(size_t)(srow + 32) * 2048 + 64 + sc8 * 8];
  __syncthreads();

  f16v o0, o1, lac;
#pragma unroll
  for (int i = 0; i < 16; ++i) { o0[i] = 0.f; o1[i] = 0.f; lac[i] = 0.f; }

  for (int kt = 0; kt < 2048; kt += 64) {
    const int cur = (kt >> 6) & 1;
    u64 mwc = bmr[kt >> 6];

    if (kt + 64 < 2048) {
      const int nxt = cur ^ 1;
      *(uint4*)&k_s[nxt][srow][sc8 * 8] = kr0;
      *(uint4*)&k_s[nxt][srow + 32][sc8 * 8] = kr1;
      *(uint4*)&v_s[nxt][srow][sc8 * 8] = vr0;
      *(uint4*)&v_s[nxt][srow + 32][sc8 * 8] = vr1;
      if (kt + 128 < 2048) {
        const int kn = kt + 128;
        kr0 = *(const uint4*)&kgb[(size_t)(kn + srow) * 64 + sc8 * 8];
        kr1 = *(const uint4*)&kgb[(size_t)(kn + srow + 32) * 64 + sc8 * 8];
        vr0 = *(const uint4*)&vgb[(size_t)srow * 2048 + kn + sc8 * 8];
        vr1 = *(const uint4*)&vgb[(size_t)(srow + 32) * 2048 + kn + sc8 * 8];
      }
    }

    // S^T = K.Q^T over HD=64 (4 k-chunks of 16)
    f16v s0, s1;
#pragma unroll
    for (int i = 0; i < 16; ++i) { s0[i] = 0.f; s1[i] = 0.f; }
#pragma unroll
    for (int c = 0; c < 4; ++c) {
      s8v ak0 = *(const s8v*)&k_s[cur][l31][c * 16 + hi * 8];
      s8v ak1 = *(const s8v*)&k_s[cur][32 + l31][c * 16 + hi * 8];
      s0 = __builtin_amdgcn_mfma_f32_32x32x16_bf16(ak0, qf[c], s0, 0, 0, 0);
      s1 = __builtin_amdgcn_mfma_f32_32x32x16_bf16(ak1, qf[c], s1, 0, 0, 0);
    }

    // p = 2^score * maskbit; rebuild PV A-frags in-register
    const u64 mq = mwc >> (4 * hi);
    s8v pf[4];
#pragma unroll
    for (int ni = 0; ni < 2; ++ni) {
      const unsigned half = (unsigned)(mq >> (32 * ni));
      float p[16];
#pragma unroll
      for (int g = 0; g < 4; ++g) {
        const unsigned nib = (half >> (8 * g)) & 0xFu;
#pragma unroll
        for (int m = 0; m < 4; ++m) {
          const float sv = (ni ? s1[g * 4 + m] : s0[g * 4 + m]);
          p[g * 4 + m] = __builtin_amdgcn_exp2f(sv) * (float)((nib >> m) & 1u);
        }
      }
#pragma unroll
      for (int kcl = 0; kcl < 2; ++kcl) {
        const int rb = 8 * kcl;
        unsigned x0 = pkbf(p[rb + 0], p[rb + 1]);
        unsigned x1 = pkbf(p[rb + 2], p[rb + 3]);
        unsigned y0 = pkbf(p[rb + 4], p[rb + 5]);
        unsigned y1 = pkbf(p[rb + 6], p[rb + 7]);
        asm("v_permlane32_swap_b32 %0, %1" : "+v"(x0), "+v"(y0));
        asm("v_permlane32_swap_b32 %0, %1" : "+v"(x1), "+v"(y1));
        union { uint4 u; s8v v; } cv;
        cv.u = make_uint4(x0, x1, y0, y1);
        pf[ni * 2 + kcl] = cv.v;
      }
    }

    // l += P @ ones (C layout identical to O)
#pragma unroll
    for (int kc = 0; kc < 4; ++kc)
      lac = __builtin_amdgcn_mfma_f32_32x32x16_bf16(pf[kc], ones, lac, 0, 0, 0);

    // O += P @ V
#pragma unroll
    for (int kc = 0; kc < 4; ++kc) {
      s8v bv0 = *(const s8v*)&v_s[cur][l31][kc * 16 + hi * 8];
      s8v bv1 = *(const s8v*)&v_s[cur][32 + l31][kc * 16 + hi * 8];
      o0 = __builtin_amdgcn_mfma_f32_32x32x16_bf16(pf[kc], bv0, o0, 0, 0, 0);
      o1 = __builtin_amdgcn_mfma_f32_32x32x16_bf16(pf[kc], bv1, o1, 0, 0, 0);
    }
    __syncthreads();
  }

  // O row r -> q_local=(r&3)+8*(r>>2)+4*hi, col=lane&31 (+32 for o1)
  const int b_ = bh >> 4, h = bh & 15;
#pragma unroll
  for (int r = 0; r < 16; ++r) {
    const int ql = (r & 3) + 8 * (r >> 2) + 4 * hi;
    const float inv = 1.f / lac[r];
    const int srw = q0 + w * 32 + ql;
    const size_t base = ((size_t)b_ * 2048 + srw) * 1024 + h * 64;
    ctx[base + l31] = f2bf(o0[r] * inv);
    ctx[base + 32 + l31] = f2bf(o1[r] * inv);
  }
}

// ---------- output projection, 64x128 tile (R6 config) ----------
__global__ __launch_bounds__(256) void gemm_out_kernel(
    const unsigned short* __restrict__ A, const unsigned short* __restrict__ Wt,
    const float* __restrict__ bias, float* __restrict__ out) {
  __shared__ __align__(16) unsigned short As[64 * 32];
  __shared__ __align__(16) unsigned short Bs[128 * 32];

  const int tid = threadIdx.x;
  const int lane = tid & 63, w = tid >> 6, ln = lane & 15, quad = lane >> 4;
  const int wm = (w & 1) * 32, wn = (w >> 1) * 64;
  const int m0 = blockIdx.x * 64, n0 = blockIdx.y * 128;

  const int slr = lane >> 2;
  const int schunk = (lane & 3) ^ ((lane >> 3) & 3);
  const int cfrag = (quad ^ ((ln >> 1) & 3)) * 8;

  f4v zero = {0.f, 0.f, 0.f, 0.f};
  f4v acc[2][4];
  for (int mi = 0; mi < 2; ++mi)
    for (int ni = 0; ni < 4; ++ni) acc[mi][ni] = zero;

  for (int kt = 0; kt < 1024; kt += 32) {
    __syncthreads();
    gll16(&A[(size_t)(m0 + w * 16 + slr) * 1024 + kt + schunk * 8],        &As[(w * 16) * 32]);
    gll16(&Wt[(size_t)(n0 + w * 32 + slr) * 1024 + kt + schunk * 8],       &Bs[(w * 32) * 32]);
    gll16(&Wt[(size_t)(n0 + w * 32 + 16 + slr) * 1024 + kt + schunk * 8],  &Bs[(w * 32 + 16) * 32]);
    __syncthreads();
    s8v a[2], b[4];
    for (int mi = 0; mi < 2; ++mi) a[mi] = *(const s8v*)&As[(wm + mi * 16 + ln) * 32 + cfrag];
    for (int ni = 0; ni < 4; ++ni) b[ni] = *(const s8v*)&Bs[(wn + ni * 16 + ln) * 32 + cfrag];
    for (int mi = 0; mi < 2; ++mi)
      for (int ni = 0; ni < 4; ++ni)
        acc[mi][ni] = __builtin_amdgcn_mfma_f32_16x16x32_bf16(a[mi], b[ni], acc[mi][ni], 0, 0, 0);
  }

  for (int mi = 0; mi < 2; ++mi) {
    int rb = m0 + wm + mi * 16 + quad * 4;
    for (int ni = 0; ni < 4; ++ni) {
      int col = n0 + wn + ni * 16 + ln;
      float bvv = bias[col];
      for (int r = 0; r < 4; ++r)
        out[(size_t)(rb + r) * 1024 + col] = acc[mi][ni][r] + bvv;
    }
  }
}

extern "C" void kernel_launch(void* const* d_in, const int* in_sizes, int n_in,
                              void* d_out, int out_size, void* d_ws, size_t ws_size,
                              hipStream_t stream) {
  const float* Q  = (const float*)d_in[0];
  const float* K  = (const float*)d_in[1];
  const float* V  = (const float*)d_in[2];
  const int* mask = (const int*)d_in[3];
  const float* Wq = (const float*)d_in[4];
  const float* bq = (const float*)d_in[5];
  const float* Wk = (const float*)d_in[6];
  const float* bk = (const float*)d_in[7];
  const float* Wv = (const float*)d_in[8];
  const float* bv = (const float*)d_in[9];
  const float* Wo = (const float*)d_in[10];
  const float* bo = (const float*)d_in[11];
  float* out = (float*)d_out;

  char* ws = (char*)d_ws;
  const size_t MB = 1u << 20;
  unsigned short* qb  = (unsigned short*)(ws + 0 * MB);
  unsigned short* kb  = (unsigned short*)(ws + 8 * MB);
  unsigned short* vb  = (unsigned short*)(ws + 16 * MB);
  unsigned short* wqt = (unsigned short*)(ws + 24 * MB);
  unsigned short* wkt = (unsigned short*)(ws + 26 * MB);
  unsigned short* wvt = (unsigned short*)(ws + 28 * MB);
  unsigned short* wot = (unsigned short*)(ws + 30 * MB);
  unsigned short* qh  = (unsigned short*)(ws + 32 * MB);
  unsigned short* kh  = (unsigned short*)(ws + 40 * MB);
  unsigned short* vth = (unsigned short*)(ws + 48 * MB);
  u64* bm             = (u64*)(ws + 56 * MB);
  unsigned short* ctx = (unsigned short*)(ws + 16 * MB);  // aliases vb (dead after proj3)

  prep_kernel<<<29696, 256, 0, stream>>>(Q, K, V, qb, kb, vb,
                                         Wq, Wk, Wv, Wo, wqt, wkt, wvt, wot,
                                         mask, bm);
  proj3_kernel<<<dim3(64, 8, 3), 256, 0, stream>>>(qb, kb, vb, wqt, wkt, wvt,
                                                   bq, bk, bv, qh, kh, vth);
  flash_kernel<<<dim3(16, 32), 256, 0, stream>>>(qh, kh, vth, bm, ctx);
  gemm_out_kernel<<<dim3(64, 8), 256, 0, stream>>>(ctx, wot, bo, out);
}

// Round 2
// 247.300 us; speedup vs baseline: 1.0674x; 1.0674x over previous
//
#include <hip/hip_runtime.h>

// MHA: B=2, S=2048, D=1024, H=16, HD=64. fp32 in/out, bf16 MFMA internally.
// ws layout (64 MB): qb/kb/vb bf16 [4096,1024] @0/8/16MB; Wq/k/v/o^T bf16
// [1024,1024] @24/26/28/30MB; q(pre-scaled 0.125*log2e),k [B,H,S,HD] @32/40MB;
// v^T [B,H,HD,S] @48MB; bmw u32 mask-words [64][32][32][2][16] @56MB (8MB);
// ctx bf16 @16MB (aliases vb).
//
// R11: flash was VALU-issue-bound at 2 waves/SIMD (VALUBusy 55%, MfmaUtil 24%
// with 32x32 MFMA = 32 cyc/SIMD each). Cuts to the VALU floor:
//  - mask applied as precomputed packed AND-words (16 v_and/iter vs ~100 ops)
//  - explicit zero-C for S-MFMA chains (no per-iter 32-reg init)
//  - __launch_bounds__(256,2): occupancy is grid-limited, let regalloc use
//    256 VGPRs (was squeezed to 92 -> AGPR shuffling)
//  - s_setprio around MFMA clusters; mask words prefetched early.

using s8v = __attribute__((ext_vector_type(8))) short;   // 8 bf16 (4 VGPRs)
using f4v = __attribute__((ext_vector_type(4))) float;   // MFMA acc (16x16)
using f16v = __attribute__((ext_vector_type(16))) float; // MFMA acc (32x32)
typedef unsigned long long u64;

__device__ __forceinline__ unsigned short f2bf(float f) {
  union { float f; unsigned int u; } v; v.f = f;
  return (unsigned short)((v.u + 0x7fffu + ((v.u >> 16) & 1u)) >> 16);  // RNE
}

// pack two f32 -> two bf16 (truncation): lo | hi<<16
__device__ __forceinline__ unsigned pkbf(float lo, float hi2) {
  return __builtin_amdgcn_perm(__float_as_uint(hi2), __float_as_uint(lo), 0x07060302);
}

__device__ __forceinline__ void gll16(const void* g, void* l) {
  __builtin_amdgcn_global_load_lds(
      (const __attribute__((address_space(1))) unsigned int*)g,
      (__attribute__((address_space(3))) unsigned int*)l, 16, 0, 0);
}

// ---------- merged prep: f2b (QKV), wtrans (4 weights), packed mask words ----------
// mask words: for flash lane (l31,hi) at (rowblk,it): 16 u32, widx = ni*8+kcl*4+e,
// word = (mask[q][k0]?0xFFFF:0) | (mask[q][k0+1]?0xFFFF0000:0),
// k0 = 64*it + 32*ni + 16*kcl + 4*hi + (e>>1)*8 + (e&1)*2, q = rowblk*32+l31.
__global__ void prep_kernel(const float* __restrict__ Q, const float* __restrict__ K,
                            const float* __restrict__ V,
                            unsigned short* __restrict__ qb, unsigned short* __restrict__ kb,
                            unsigned short* __restrict__ vb,
                            const float* __restrict__ W0, const float* __restrict__ W1,
                            const float* __restrict__ W2, const float* __restrict__ W3,
                            unsigned short* __restrict__ T0, unsigned short* __restrict__ T1,
                            unsigned short* __restrict__ T2, unsigned short* __restrict__ T3,
                            const int* __restrict__ mask, unsigned* __restrict__ bmw) {
  __shared__ unsigned short t[64][72];
  const int bid = blockIdx.x, tid = threadIdx.x;
  if (bid < 12288) {
    int z = bid >> 12;
    int idx = (bid & 4095) * 256 + tid;
    const float* in = (z == 0) ? Q : (z == 1) ? K : V;
    unsigned short* out = (z == 0) ? qb : (z == 1) ? kb : vb;
    float4 v = ((const float4*)in)[idx];
    ushort4 o;
    o.x = f2bf(v.x); o.y = f2bf(v.y); o.z = f2bf(v.z); o.w = f2bf(v.w);
    ((ushort4*)out)[idx] = o;
  } else if (bid < 13312) {
    int b = bid - 12288;
    int z = b >> 8, rem = b & 255;
    int k0 = (rem >> 4) * 64, n0 = (rem & 15) * 64;
    const float* W = (z == 0) ? W0 : (z == 1) ? W1 : (z == 2) ? W2 : W3;
    unsigned short* Wt = (z == 0) ? T0 : (z == 1) ? T1 : (z == 2) ? T2 : T3;
    for (int p = 0; p < 4; ++p) {
      int idx = p * 256 + tid;
      int row = idx >> 4, c4 = idx & 15;
      float4 v = *(const float4*)&W[(size_t)(k0 + row) * 1024 + n0 + c4 * 4];
      t[row][c4 * 4 + 0] = f2bf(v.x);
      t[row][c4 * 4 + 1] = f2bf(v.y);
      t[row][c4 * 4 + 2] = f2bf(v.z);
      t[row][c4 * 4 + 3] = f2bf(v.w);
    }
    __syncthreads();
    for (int p = 0; p < 2; ++p) {
      int idx = p * 256 + tid;
      int j = idx >> 3, c8 = idx & 7;
      unsigned short tmp[8];
      for (int i = 0; i < 8; ++i) tmp[i] = t[c8 * 8 + i][j];
      uint4 o;
      o.x = tmp[0] | ((unsigned)tmp[1] << 16);
      o.y = tmp[2] | ((unsigned)tmp[3] << 16);
      o.z = tmp[4] | ((unsigned)tmp[5] << 16);
      o.w = tmp[6] | ((unsigned)tmp[7] << 16);
      *(uint4*)&Wt[(size_t)(n0 + j) * 1024 + k0 + c8 * 8] = o;
    }
  } else {
    int g = (bid - 13312) * 256 + tid;          // [0, 2^21)
    int widx = g & 15, hi = (g >> 4) & 1, l31 = (g >> 5) & 31;
    int it = (g >> 10) & 31, rowblk = g >> 15;
    int ni = widx >> 3, kcl = (widx >> 2) & 1, e = widx & 3;
    int kk = 64 * it + 32 * ni + 16 * kcl + 4 * hi + (e >> 1) * 8 + (e & 1) * 2;
    int qrow = rowblk * 32 + l31;
    const int* mrow = mask + (size_t)qrow * 2048 + kk;
    unsigned wd = (mrow[0] ? 0xFFFFu : 0u) | (mrow[1] ? 0xFFFF0000u : 0u);
    bmw[g] = wd;
  }
}

// ---------- fused QKV projection GEMM, 64x128 tile (R6 config) ----------
// z=0: q*(0.125*log2e) -> [B,H,S,HD]; z=1: k -> [B,H,S,HD]; z=2: v -> v^T [B,H,HD,S]
__global__ __launch_bounds__(256) void proj3_kernel(
    const unsigned short* __restrict__ A0, const unsigned short* __restrict__ A1,
    const unsigned short* __restrict__ A2,
    const unsigned short* __restrict__ W0, const unsigned short* __restrict__ W1,
    const unsigned short* __restrict__ W2,
    const float* __restrict__ b0, const float* __restrict__ b1, const float* __restrict__ b2,
    unsigned short* __restrict__ oq, unsigned short* __restrict__ ok,
    unsigned short* __restrict__ ovt) {
  const int z = blockIdx.z;
  const unsigned short* A  = (z == 0) ? A0 : (z == 1) ? A1 : A2;
  const unsigned short* Wt = (z == 0) ? W0 : (z == 1) ? W1 : W2;
  const float* bias        = (z == 0) ? b0 : (z == 1) ? b1 : b2;

  __shared__ __align__(16) unsigned short As[64 * 32];
  __shared__ __align__(16) unsigned short Bs[128 * 32];

  const int tid = threadIdx.x;
  const int lane = tid & 63, w = tid >> 6, ln = lane & 15, quad = lane >> 4;
  const int wm = (w & 1) * 32, wn = (w >> 1) * 64;
  const int m0 = blockIdx.x * 64, n0 = blockIdx.y * 128;

  const int slr = lane >> 2;
  const int schunk = (lane & 3) ^ ((lane >> 3) & 3);
  const int cfrag = (quad ^ ((ln >> 1) & 3)) * 8;

  f4v zero = {0.f, 0.f, 0.f, 0.f};
  f4v acc[2][4];
  for (int mi = 0; mi < 2; ++mi)
    for (int ni = 0; ni < 4; ++ni) acc[mi][ni] = zero;

  for (int kt = 0; kt < 1024; kt += 32) {
    __syncthreads();
    gll16(&A[(size_t)(m0 + w * 16 + slr) * 1024 + kt + schunk * 8],        &As[(w * 16) * 32]);
    gll16(&Wt[(size_t)(n0 + w * 32 + slr) * 1024 + kt + schunk * 8],       &Bs[(w * 32) * 32]);
    gll16(&Wt[(size_t)(n0 + w * 32 + 16 + slr) * 1024 + kt + schunk * 8],  &Bs[(w * 32 + 16) * 32]);
    __syncthreads();
    s8v a[2], b[4];
    for (int mi = 0; mi < 2; ++mi) a[mi] = *(const s8v*)&As[(wm + mi * 16 + ln) * 32 + cfrag];
    for (int ni = 0; ni < 4; ++ni) b[ni] = *(const s8v*)&Bs[(wn + ni * 16 + ln) * 32 + cfrag];
    if (z < 2) {
      for (int mi = 0; mi < 2; ++mi)
        for (int ni = 0; ni < 4; ++ni)
          acc[mi][ni] = __builtin_amdgcn_mfma_f32_16x16x32_bf16(a[mi], b[ni], acc[mi][ni], 0, 0, 0);
    } else {
      for (int mi = 0; mi < 2; ++mi)
        for (int ni = 0; ni < 4; ++ni)
          acc[mi][ni] = __builtin_amdgcn_mfma_f32_16x16x32_bf16(b[ni], a[mi], acc[mi][ni], 0, 0, 0);
    }
  }

  if (z < 2) {
    const float qscale = (z == 0) ? 0.18033688f : 1.0f;  // 0.125 * log2(e)
    unsigned short* outp = (z == 0) ? oq : ok;
    for (int mi = 0; mi < 2; ++mi) {
      int rb = m0 + wm + mi * 16 + quad * 4;
      int b_ = rb >> 11;
      for (int ni = 0; ni < 4; ++ni) {
        int col = n0 + wn + ni * 16 + ln;
        float bvv = bias[col];
        int h = col >> 6, hd = col & 63;
        size_t ob = (size_t)(b_ * 16 + h) * 2048;
        for (int r = 0; r < 4; ++r) {
          int s = (rb + r) & 2047;
          outp[(ob + s) * 64 + hd] = f2bf((acc[mi][ni][r] + bvv) * qscale);
        }
      }
    }
  } else {
    for (int ni = 0; ni < 4; ++ni) {
      for (int r = 0; r < 4; ++r) {
        int colw = n0 + wn + ni * 16 + quad * 4 + r;
        int h = colw >> 6, hd = colw & 63;
        float bvv = bias[colw];
        for (int mi = 0; mi < 2; ++mi) {
          int sg = m0 + wm + mi * 16 + ln;
          int b_ = sg >> 11, ss = sg & 2047;
          ovt[((size_t)(b_ * 16 + h) * 64 + hd) * 2048 + ss] = f2bf(acc[mi][ni][r] + bvv);
        }
      }
    }
  }
}

// ---------- flash attention R11: 256 threads, 4 waves x 32 q-rows, 32x32x16 ----------
__global__ __launch_bounds__(256, 2) void flash_kernel(
    const unsigned short* __restrict__ q, const unsigned short* __restrict__ k,
    const unsigned short* __restrict__ vt, const unsigned* __restrict__ bmw,
    unsigned short* __restrict__ ctx) {
  __shared__ __align__(16) unsigned short k_s[2][64][72];
  __shared__ __align__(16) unsigned short v_s[2][64][72];

  const int tid = threadIdx.x;
  const int lane = tid & 63, w = tid >> 6;
  const int l31 = lane & 31, hi = lane >> 5;
  const int q0 = blockIdx.x * 128;
  const int bh = blockIdx.y;
  const unsigned short* qg  = q  + ((size_t)bh * 2048 + q0) * 64;
  const unsigned short* kgb = k  + (size_t)bh * 2048 * 64;
  const unsigned short* vgb = vt + (size_t)bh * 64 * 2048;
  // mask-word base for this lane: bmw[rowblk][it][l31][hi][16]
  const unsigned* mwp = bmw + (size_t)(blockIdx.x * 4 + w) * 32768 + l31 * 32 + hi * 16;

  // Q fragments direct from global: wave w owns q-rows [w*32, w*32+32)
  const int qrow = w * 32 + l31;
  s8v qf[4];
#pragma unroll
  for (int c = 0; c < 4; ++c)
    qf[c] = *(const s8v*)&qg[(size_t)qrow * 64 + c * 16 + hi * 8];

  // ones fragment for l = P @ ones; zero C for S chains
  s8v ones;
#pragma unroll
  for (int i = 0; i < 8; ++i) ones[i] = (short)0x3F80;
  f16v zf;
#pragma unroll
  for (int i = 0; i < 16; ++i) zf[i] = 0.f;

  // staging: 256 threads x 2 uint4 per array per tile
  const int srow = tid >> 3, sc8 = tid & 7;  // rows srow and srow+32

  // tile 0 -> LDS buf 0; prefetch tile 1 into regs
  uint4 kr0 = *(const uint4*)&kgb[(size_t)srow * 64 + sc8 * 8];
  uint4 kr1 = *(const uint4*)&kgb[(size_t)(srow + 32) * 64 + sc8 * 8];
  uint4 vr0 = *(const uint4*)&vgb[(size_t)srow * 2048 + sc8 * 8];
  uint4 vr1 = *(const uint4*)&vgb[(size_t)(srow + 32) * 2048 + sc8 * 8];
  *(uint4*)&k_s[0][srow][sc8 * 8] = kr0;
  *(uint4*)&k_s[0][srow + 32][sc8 * 8] = kr1;
  *(uint4*)&v_s[0][srow][sc8 * 8] = vr0;
  *(uint4*)&v_s[0][srow + 32][sc8 * 8] = vr1;
  kr0 = *(const uint4*)&kgb[(size_t)(64 + srow) * 64 + sc8 * 8];
  kr1 = *(const uint4*)&kgb[(size_t)(64 + srow + 32) * 64 + sc8 * 8];
  vr0 = *(const uint4*)&vgb[(size_t)srow * 2048 + 64 + sc8 * 8];
  vr1 = *(const uint4*)&vgb[(size_t)(srow + 32) * 2048 + 64 + sc8 * 8];
  __syncthreads();

  f16v o0, o1, lac;
#pragma unroll
  for (int i = 0; i < 16; ++i) { o0[i] = 0.f; o1[i] = 0.f; lac[i] = 0.f; }

  for (int kt = 0; kt < 2048; kt += 64) {
    const int cur = (kt >> 6) & 1;
    // prefetch mask words for this tile (used ~300+ cycles later)
    const uint4* mw4 = (const uint4*)(mwp + (kt >> 6) * 1024);
    const uint4 mwA = mw4[0], mwB = mw4[1], mwC = mw4[2], mwD = mw4[3];

    if (kt + 64 < 2048) {
      const int nxt = cur ^ 1;
      *(uint4*)&k_s[nxt][srow][sc8 * 8] = kr0;
      *(uint4*)&k_s[nxt][srow + 32][sc8 * 8] = kr1;
      *(uint4*)&v_s[nxt][srow][sc8 * 8] = vr0;
      *(uint4*)&v_s[nxt][srow + 32][sc8 * 8] = vr1;
      if (kt + 128 < 2048) {
        const int kn = kt + 128;
        kr0 = *(const uint4*)&kgb[(size_t)(kn + srow) * 64 + sc8 * 8];
        kr1 = *(const uint4*)&kgb[(size_t)(kn + srow + 32) * 64 + sc8 * 8];
        vr0 = *(const uint4*)&vgb[(size_t)srow * 2048 + kn + sc8 * 8];
        vr1 = *(const uint4*)&vgb[(size_t)(srow + 32) * 2048 + kn + sc8 * 8];
      }
    }

    // S^T = K.Q^T over HD=64 (zero-C first chunk, accumulate 3 more)
    __builtin_amdgcn_s_setprio(1);
    s8v ak0 = *(const s8v*)&k_s[cur][l31][hi * 8];
    s8v ak1 = *(const s8v*)&k_s[cur][32 + l31][hi * 8];
    f16v s0 = __builtin_amdgcn_mfma_f32_32x32x16_bf16(ak0, qf[0], zf, 0, 0, 0);
    f16v s1 = __builtin_amdgcn_mfma_f32_32x32x16_bf16(ak1, qf[0], zf, 0, 0, 0);
#pragma unroll
    for (int c = 1; c < 4; ++c) {
      ak0 = *(const s8v*)&k_s[cur][l31][c * 16 + hi * 8];
      ak1 = *(const s8v*)&k_s[cur][32 + l31][c * 16 + hi * 8];
      s0 = __builtin_amdgcn_mfma_f32_32x32x16_bf16(ak0, qf[c], s0, 0, 0, 0);
      s1 = __builtin_amdgcn_mfma_f32_32x32x16_bf16(ak1, qf[c], s1, 0, 0, 0);
    }
    __builtin_amdgcn_s_setprio(0);

    // p = 2^score; mask applied as AND on packed bf16 pairs; rebuild PV A-frags
    s8v pf[4];
#pragma unroll
    for (int ni = 0; ni < 2; ++ni) {
      float p[16];
#pragma unroll
      for (int i = 0; i < 16; ++i)
        p[i] = __builtin_amdgcn_exp2f(ni ? s1[i] : s0[i]);
#pragma unroll
      for (int kcl = 0; kcl < 2; ++kcl) {
        const int rb = 8 * kcl;
        const uint4 mw = ni ? (kcl ? mwD : mwC) : (kcl ? mwB : mwA);
        unsigned x0 = pkbf(p[rb + 0], p[rb + 1]) & mw.x;
        unsigned x1 = pkbf(p[rb + 2], p[rb + 3]) & mw.y;
        unsigned y0 = pkbf(p[rb + 4], p[rb + 5]) & mw.z;
        unsigned y1 = pkbf(p[rb + 6], p[rb + 7]) & mw.w;
        asm("v_permlane32_swap_b32 %0, %1" : "+v"(x0), "+v"(y0));
        asm("v_permlane32_swap_b32 %0, %1" : "+v"(x1), "+v"(y1));
        union { uint4 u; s8v v; } cv;
        cv.u = make_uint4(x0, x1, y0, y1);
        pf[ni * 2 + kcl] = cv.v;
      }
    }

    // l += P @ ones; O += P @ V
    __builtin_amdgcn_s_setprio(1);
#pragma unroll
    for (int kc = 0; kc < 4; ++kc)
      lac = __builtin_amdgcn_mfma_f32_32x32x16_bf16(pf[kc], ones, lac, 0, 0, 0);
#pragma unroll
    for (int kc = 0; kc < 4; ++kc) {
      s8v bv0 = *(const s8v*)&v_s[cur][l31][kc * 16 + hi * 8];
      s8v bv1 = *(const s8v*)&v_s[cur][32 + l31][kc * 16 + hi * 8];
      o0 = __builtin_amdgcn_mfma_f32_32x32x16_bf16(pf[kc], bv0, o0, 0, 0, 0);
      o1 = __builtin_amdgcn_mfma_f32_32x32x16_bf16(pf[kc], bv1, o1, 0, 0, 0);
    }
    __builtin_amdgcn_s_setprio(0);
    __syncthreads();
  }

  // O row r -> q_local=(r&3)+8*(r>>2)+4*hi, col=lane&31 (+32 for o1)
  const int b_ = bh >> 4, h = bh & 15;
#pragma unroll
  for (int r = 0; r < 16; ++r) {
    const int ql = (r & 3) + 8 * (r >> 2) + 4 * hi;
    const float inv = 1.f / lac[r];
    const int srw = q0 + w * 32 + ql;
    const size_t base = ((size_t)b_ * 2048 + srw) * 1024 + h * 64;
    ctx[base + l31] = f2bf(o0[r] * inv);
    ctx[base + 32 + l31] = f2bf(o1[r] * inv);
  }
}

// ---------- output projection, 64x128 tile (R6 config) ----------
__global__ __launch_bounds__(256) void gemm_out_kernel(
    const unsigned short* __restrict__ A, const unsigned short* __restrict__ Wt,
    const float* __restrict__ bias, float* __restrict__ out) {
  __shared__ __align__(16) unsigned short As[64 * 32];
  __shared__ __align__(16) unsigned short Bs[128 * 32];

  const int tid = threadIdx.x;
  const int lane = tid & 63, w = tid >> 6, ln = lane & 15, quad = lane >> 4;
  const int wm = (w & 1) * 32, wn = (w >> 1) * 64;
  const int m0 = blockIdx.x * 64, n0 = blockIdx.y * 128;

  const int slr = lane >> 2;
  const int schunk = (lane & 3) ^ ((lane >> 3) & 3);
  const int cfrag = (quad ^ ((ln >> 1) & 3)) * 8;

  f4v zero = {0.f, 0.f, 0.f, 0.f};
  f4v acc[2][4];
  for (int mi = 0; mi < 2; ++mi)
    for (int ni = 0; ni < 4; ++ni) acc[mi][ni] = zero;

  for (int kt = 0; kt < 1024; kt += 32) {
    __syncthreads();
    gll16(&A[(size_t)(m0 + w * 16 + slr) * 1024 + kt + schunk * 8],        &As[(w * 16) * 32]);
    gll16(&Wt[(size_t)(n0 + w * 32 + slr) * 1024 + kt + schunk * 8],       &Bs[(w * 32) * 32]);
    gll16(&Wt[(size_t)(n0 + w * 32 + 16 + slr) * 1024 + kt + schunk * 8],  &Bs[(w * 32 + 16) * 32]);
    __syncthreads();
    s8v a[2], b[4];
    for (int mi = 0; mi < 2; ++mi) a[mi] = *(const s8v*)&As[(wm + mi * 16 + ln) * 32 + cfrag];
    for (int ni = 0; ni < 4; ++ni) b[ni] = *(const s8v*)&Bs[(wn + ni * 16 + ln) * 32 + cfrag];
    for (int mi = 0; mi < 2; ++mi)
      for (int ni = 0; ni < 4; ++ni)
        acc[mi][ni] = __builtin_amdgcn_mfma_f32_16x16x32_bf16(a[mi], b[ni], acc[mi][ni], 0, 0, 0);
  }

  for (int mi = 0; mi < 2; ++mi) {
    int rb = m0 + wm + mi * 16 + quad * 4;
    for (int ni = 0; ni < 4; ++ni) {
      int col = n0 + wn + ni * 16 + ln;
      float bvv = bias[col];
      for (int r = 0; r < 4; ++r)
        out[(size_t)(rb + r) * 1024 + col] = acc[mi][ni][r] + bvv;
    }
  }
}

extern "C" void kernel_launch(void* const* d_in, const int* in_sizes, int n_in,
                              void* d_out, int out_size, void* d_ws, size_t ws_size,
                              hipStream_t stream) {
  const float* Q  = (const float*)d_in[0];
  const float* K  = (const float*)d_in[1];
  const float* V  = (const float*)d_in[2];
  const int* mask = (const int*)d_in[3];
  const float* Wq = (const float*)d_in[4];
  const float* bq = (const float*)d_in[5];
  const float* Wk = (const float*)d_in[6];
  const float* bk = (const float*)d_in[7];
  const float* Wv = (const float*)d_in[8];
  const float* bv = (const float*)d_in[9];
  const float* Wo = (const float*)d_in[10];
  const float* bo = (const float*)d_in[11];
  float* out = (float*)d_out;

  char* ws = (char*)d_ws;
  const size_t MB = 1u << 20;
  unsigned short* qb  = (unsigned short*)(ws + 0 * MB);
  unsigned short* kb  = (unsigned short*)(ws + 8 * MB);
  unsigned short* vb  = (unsigned short*)(ws + 16 * MB);
  unsigned short* wqt = (unsigned short*)(ws + 24 * MB);
  unsigned short* wkt = (unsigned short*)(ws + 26 * MB);
  unsigned short* wvt = (unsigned short*)(ws + 28 * MB);
  unsigned short* wot = (unsigned short*)(ws + 30 * MB);
  unsigned short* qh  = (unsigned short*)(ws + 32 * MB);
  unsigned short* kh  = (unsigned short*)(ws + 40 * MB);
  unsigned short* vth = (unsigned short*)(ws + 48 * MB);
  unsigned* bmw       = (unsigned*)(ws + 56 * MB);       // 8 MB of packed mask words
  unsigned short* ctx = (unsigned short*)(ws + 16 * MB);  // aliases vb (dead after proj3)

  prep_kernel<<<21504, 256, 0, stream>>>(Q, K, V, qb, kb, vb,
                                         Wq, Wk, Wv, Wo, wqt, wkt, wvt, wot,
                                         mask, bmw);
  proj3_kernel<<<dim3(64, 8, 3), 256, 0, stream>>>(qb, kb, vb, wqt, wkt, wvt,
                                                   bq, bk, bv, qh, kh, vth);
  flash_kernel<<<dim3(16, 32), 256, 0, stream>>>(qh, kh, vth, bmw, ctx);
  gemm_out_kernel<<<dim3(64, 8), 256, 0, stream>>>(ctx, wot, bo, out);
}